// Round 3
// baseline (6124.855 us; speedup 1.0000x reference)
//
#include <hip/hip_runtime.h>
#include <hip/hip_bf16.h>

// ---------------------------------------------------------------------------
// PointNet++ encoder (4 SA stages) for MI355X.
// Pipeline per stage: FPS -> gather new_xyz -> ball query -> fused group+MLP+maxpool.
// FPS / ball-query distance math matches numpy per-op IEEE semantics exactly
// (argmax selection must be exact; xyz output is raw copies).
// ---------------------------------------------------------------------------

#define B_SZ 4

typedef float v2f __attribute__((ext_vector_type(2)));

// Packed-FP32 helpers (VOP3P). Each half is a plain IEEE f32 op, so results
// are bitwise identical to scalar v_add_f32/v_mul_f32.
__device__ __forceinline__ v2f pk_add(v2f a, v2f b) {
  v2f d;
  asm("v_pk_add_f32 %0, %1, %2" : "=v"(d) : "v"(a), "v"(b));
  return d;
}
__device__ __forceinline__ v2f pk_mul(v2f a, v2f b) {
  v2f d;
  asm("v_pk_mul_f32 %0, %1, %2" : "=v"(d) : "v"(a), "v"(b));
  return d;
}

// ------------------------------- FPS ---------------------------------------
// One block per batch; ONE barrier per iteration.
// Per-thread: packed-fp32 distance update (2 points per instruction bundle),
// argmax tracked as (float, k) in 4 contiguous-k chains (strict > keeps the
// first occurrence = smallest index). Packed u64 (dist_bits<<32 | N-idx) is
// built once per thread, wave-reduced by shuffle, then NW wave results are
// combined by a redundant LDS scan (no second barrier; double-buffered slots).
template <int N, int NPOINT, int T, bool XYZ_IN_LDS>
__global__ __launch_bounds__(T) void fps_kernel(const float* __restrict__ xyz,
                                                int* __restrict__ fidx) {
#pragma clang fp contract(off)
  constexpr int PT = N / T;
  static_assert(PT % 2 == 0, "PT even");
  constexpr int NP2 = PT / 2;
  constexpr int NW = T / 64;
  constexpr int NCH = (NP2 >= 4) ? 4 : NP2;  // independent tracking chains
  constexpr int CW = NP2 / NCH;              // pairs per chain (contiguous k)
  constexpr int LN = XYZ_IN_LDS ? N : 1;
  const int b = blockIdx.x;
  const int t = threadIdx.x;
  const int lane = t & 63;
  const int wv = t >> 6;
  const float* base = xyz + (size_t)b * N * 3;

  v2f px[NP2], py[NP2], pz[NP2], dv[NP2];
  __shared__ __align__(16) unsigned long long s_pack[2][NW];
  __shared__ float s_x[LN], s_y[LN], s_z[LN];

#pragma unroll
  for (int j = 0; j < NP2; ++j) {
    int i0 = t + (2 * j) * T;
    int i1 = t + (2 * j + 1) * T;
    px[j][0] = base[i0 * 3 + 0];
    py[j][0] = base[i0 * 3 + 1];
    pz[j][0] = base[i0 * 3 + 2];
    px[j][1] = base[i1 * 3 + 0];
    py[j][1] = base[i1 * 3 + 1];
    pz[j][1] = base[i1 * 3 + 2];
    dv[j][0] = 1e10f;
    dv[j][1] = 1e10f;
    if constexpr (XYZ_IN_LDS) {
      s_x[i0] = px[j][0];
      s_y[i0] = py[j][0];
      s_z[i0] = pz[j][0];
      s_x[i1] = px[j][1];
      s_y[i1] = py[j][1];
      s_z[i1] = pz[j][1];
    }
  }
  __syncthreads();

  int far = 0;
  int p = 0;
  for (int it = 0; it < NPOINT; ++it) {
    if (t == 0) fidx[b * NPOINT + it] = far;
    float cx, cy, cz;
    if constexpr (XYZ_IN_LDS) {
      cx = s_x[far];
      cy = s_y[far];
      cz = s_z[far];
    } else {
      cx = base[far * 3 + 0];
      cy = base[far * 3 + 1];
      cz = base[far * 3 + 2];
    }
    // (p - c) computed as p + (-c): bitwise identical to IEEE subtraction.
    const float nx = -cx, ny = -cy, nz = -cz;
    const v2f c2x = {nx, nx}, c2y = {ny, ny}, c2z = {nz, nz};

    float best[NCH];
    int bk[NCH];
#pragma unroll
    for (int q = 0; q < NCH; ++q) {
      best[q] = -1.0f;
      bk[q] = 0;
    }

#pragma unroll
    for (int j = 0; j < NP2; ++j) {
      constexpr int dummy = 0;
      (void)dummy;
      v2f dx = pk_add(px[j], c2x);
      v2f dy = pk_add(py[j], c2y);
      v2f dz = pk_add(pz[j], c2z);
      v2f xx = pk_mul(dx, dx);
      v2f yy = pk_mul(dy, dy);
      v2f zz = pk_mul(dz, dz);
      v2f s = pk_add(xx, yy);
      v2f d = pk_add(s, zz);
      v2f nd;
      nd[0] = fminf(dv[j][0], d[0]);
      nd[1] = fminf(dv[j][1], d[1]);
      dv[j] = nd;
      const int q = j / CW;  // compile-time (loop unrolled)
      if (nd[0] > best[q]) {
        best[q] = nd[0];
        bk[q] = 2 * j;
      }
      if (nd[1] > best[q]) {
        best[q] = nd[1];
        bk[q] = 2 * j + 1;
      }
    }
    // merge chains in ascending-k order; strict > keeps smallest index on tie
    float bb = best[0];
    int kk = bk[0];
#pragma unroll
    for (int q = 1; q < NCH; ++q) {
      if (best[q] > bb) {
        bb = best[q];
        kk = bk[q];
      }
    }
    int idx = t + kk * T;
    unsigned long long P =
        ((unsigned long long)__float_as_uint(bb) << 32) |
        (unsigned int)(N - idx);
    // wave max-reduce on packed u64
#pragma unroll
    for (int off = 32; off > 0; off >>= 1) {
      unsigned long long o = __shfl_xor(P, off);
      P = o > P ? o : P;
    }
    if (lane == 0) s_pack[p][wv] = P;
    __syncthreads();
    unsigned long long bbp = s_pack[p][0];
#pragma unroll
    for (int w = 1; w < NW; ++w) {
      unsigned long long v = s_pack[p][w];
      bbp = v > bbp ? v : bbp;
    }
    far = N - (int)(unsigned int)(bbp & 0xffffffffull);
    p ^= 1;
  }
}

// --------------------------- gather new_xyz --------------------------------
__global__ void gather_xyz_kernel(const float* __restrict__ xyz,
                                  const int* __restrict__ fidx,
                                  float* __restrict__ out, int N, int S) {
  int s = blockIdx.x * blockDim.x + threadIdx.x;
  int b = blockIdx.y;
  if (s < S) {
    int i = fidx[b * S + s];
    out[((size_t)(b * S + s)) * 3 + 0] = xyz[((size_t)(b * N + i)) * 3 + 0];
    out[((size_t)(b * S + s)) * 3 + 1] = xyz[((size_t)(b * N + i)) * 3 + 1];
    out[((size_t)(b * S + s)) * 3 + 2] = xyz[((size_t)(b * N + i)) * 3 + 2];
  }
}

// ----------------------------- ball query ----------------------------------
// One wave per query point. Scan N points in 64-chunks; ballot-ordered append
// of in-ball indices (ascending index = reference's sort semantics); pad with
// first neighbor. d2 formula replicates (|c|^2 + |x|^2) - 2*dot, contract off.
template <int N, int NS>
__global__ __launch_bounds__(256) void ball_query_kernel(
    const float* __restrict__ xyz, const float* __restrict__ new_xyz,
    int* __restrict__ nidx, int S, float r2) {
#pragma clang fp contract(off)
  const int wv = threadIdx.x >> 6;
  const int lane = threadIdx.x & 63;
  const int b = blockIdx.y;
  const int s = blockIdx.x * 4 + wv;
  __shared__ int s_idx[4][NS];
  const float* base = xyz + (size_t)b * N * 3;

  float cx = new_xyz[((size_t)(b * S + s)) * 3 + 0];
  float cy = new_xyz[((size_t)(b * S + s)) * 3 + 1];
  float cz = new_xyz[((size_t)(b * S + s)) * 3 + 2];
  float sc = (cx * cx + cy * cy) + cz * cz;

  int found = 0;
  for (int i0 = 0; i0 < N && found < NS; i0 += 64) {  // N % 64 == 0 always
    int i = i0 + lane;
    float x = base[i * 3 + 0];
    float y = base[i * 3 + 1];
    float z = base[i * 3 + 2];
    float sx = (x * x + y * y) + z * z;
    float dt = (cx * x + cy * y) + cz * z;
    float d2 = (sc + sx) - 2.0f * dt;
    bool inb = d2 < r2;
    unsigned long long m = __ballot(inb);
    if (inb) {
      int pos = found + __popcll(m & ((1ull << lane) - 1));
      if (pos < NS) s_idx[wv][pos] = i;
    }
    found += __popcll(m);
  }
  __syncthreads();
  int fcnt = found < NS ? found : NS;
  int first = s_idx[wv][0];
  int* outp = nidx + ((size_t)(b * S + s)) * NS;
  for (int j = lane; j < NS; j += 64) outp[j] = (j < fcnt) ? s_idx[wv][j] : first;
}

// --------------------------- fused group MLP -------------------------------
// act[R][CMAXP] in LDS holds activations in-place across the 3 layers.
// Thread grid RG x CG; each thread owns RPT rows x CPT cols; W streamed from
// L1/L2 (each W element feeds RPT FMAs).
template <int R, int RG, int CG, int CMAXP, int CIN, int COUT>
__device__ __forceinline__ void mlp_layer(float* act, const float* __restrict__ w,
                                          const float* __restrict__ bias, int tid) {
  constexpr int RPT = R / RG;
  constexpr int CPT = COUT / CG;
  static_assert(RG * CG == 256, "thread grid");
  const int rg = tid / CG;
  const int cg = tid % CG;

  float acc[RPT][CPT];
#pragma unroll
  for (int rr = 0; rr < RPT; ++rr)
#pragma unroll
    for (int cc = 0; cc < CPT; ++cc) acc[rr][cc] = 0.f;

  constexpr int K4 = (CIN / 4) * 4;
  for (int k = 0; k < K4; k += 4) {
    float4 a[RPT];
#pragma unroll
    for (int rr = 0; rr < RPT; ++rr)
      a[rr] = *(const float4*)(&act[(rg * RPT + rr) * CMAXP + k]);
    float wvv[4][CPT];
#pragma unroll
    for (int kk = 0; kk < 4; ++kk)
#pragma unroll
      for (int cc = 0; cc < CPT; ++cc)
        wvv[kk][cc] = w[(size_t)(k + kk) * COUT + cg + cc * CG];
#pragma unroll
    for (int rr = 0; rr < RPT; ++rr) {
      float4 av = a[rr];
#pragma unroll
      for (int cc = 0; cc < CPT; ++cc) {
        acc[rr][cc] += av.x * wvv[0][cc];
        acc[rr][cc] += av.y * wvv[1][cc];
        acc[rr][cc] += av.z * wvv[2][cc];
        acc[rr][cc] += av.w * wvv[3][cc];
      }
    }
  }
#pragma unroll 1
  for (int k = K4; k < CIN; ++k) {
    float wvv[CPT];
#pragma unroll
    for (int cc = 0; cc < CPT; ++cc) wvv[cc] = w[(size_t)k * COUT + cg + cc * CG];
#pragma unroll
    for (int rr = 0; rr < RPT; ++rr) {
      float av = act[(rg * RPT + rr) * CMAXP + k];
#pragma unroll
      for (int cc = 0; cc < CPT; ++cc) acc[rr][cc] += av * wvv[cc];
    }
  }
  __syncthreads();  // all reads of act done before in-place overwrite
#pragma unroll
  for (int rr = 0; rr < RPT; ++rr)
#pragma unroll
    for (int cc = 0; cc < CPT; ++cc) {
      int co = cg + cc * CG;
      float v = acc[rr][cc] + bias[co];
      act[(rg * RPT + rr) * CMAXP + co] = fmaxf(v, 0.f);
    }
  __syncthreads();
}

template <int NS, int G, int CPREV, int CO0, int CO1, int CO2, int RG, int CG, int CMAXP>
__global__ __launch_bounds__(256) void group_mlp_kernel(
    const float* __restrict__ xyz, const float* __restrict__ new_xyz,
    const float* __restrict__ feats, const int* __restrict__ nidx,
    const float* __restrict__ w0, const float* __restrict__ b0,
    const float* __restrict__ w1, const float* __restrict__ b1,
    const float* __restrict__ w2, const float* __restrict__ b2,
    float* __restrict__ out, int N, int S, float radius) {
  constexpr int R = NS * G;
  constexpr int CIN = 3 + CPREV;
  __shared__ __align__(16) float act[R * CMAXP];
  const int tid = threadIdx.x;
  const int b = blockIdx.y;
  const int s0 = blockIdx.x * G;

  // stage inputs: rel xyz (exact sub + div by radius) and gathered feats
  for (int i = tid; i < R * CIN; i += 256) {
    int row = i / CIN;
    int ch = i - row * CIN;
    int g = row / NS;
    int j = row - g * NS;
    int sidx = s0 + g;
    int n = nidx[((size_t)(b * S + sidx)) * NS + j];
    float v;
    if constexpr (CPREV == 0) {
      v = (xyz[((size_t)(b * N + n)) * 3 + ch] -
           new_xyz[((size_t)(b * S + sidx)) * 3 + ch]) /
          radius;
    } else {
      if (ch < 3) {
        v = (xyz[((size_t)(b * N + n)) * 3 + ch] -
             new_xyz[((size_t)(b * S + sidx)) * 3 + ch]) /
            radius;
      } else {
        v = feats[((size_t)(b * N + n)) * CPREV + (ch - 3)];
      }
    }
    act[row * CMAXP + ch] = v;
  }
  __syncthreads();

  mlp_layer<R, RG, CG, CMAXP, CIN, CO0>(act, w0, b0, tid);
  mlp_layer<R, RG, CG, CMAXP, CO0, CO1>(act, w1, b1, tid);
  mlp_layer<R, RG, CG, CMAXP, CO1, CO2>(act, w2, b2, tid);

  // maxpool over NS neighbors per group
  for (int i = tid; i < G * CO2; i += 256) {
    int g = i / CO2;
    int co = i - g * CO2;
    float m = act[(g * NS) * CMAXP + co];
    for (int j = 1; j < NS; ++j) m = fmaxf(m, act[(g * NS + j) * CMAXP + co]);
    out[((size_t)(b * S + s0 + g)) * CO2 + co] = m;
  }
}

// ---------------------------------------------------------------------------
extern "C" void kernel_launch(void* const* d_in, const int* in_sizes, int n_in,
                              void* d_out, int out_size, void* d_ws, size_t ws_size,
                              hipStream_t stream) {
  (void)in_sizes; (void)n_in; (void)out_size; (void)ws_size;
  const float* pc = (const float*)d_in[0];
  const float* W[4][3];
  const float* Bb[4][3];
  for (int s = 0; s < 4; ++s)
    for (int l = 0; l < 3; ++l) {
      W[s][l] = (const float*)d_in[1 + s * 6 + l * 2];
      Bb[s][l] = (const float*)d_in[2 + s * 6 + l * 2];
    }

  // workspace layout (bytes): fidx 32KB | nidx 2MB | xyzA 96KB | xyzB 96KB |
  // featA 4MB | featB 4MB   (total ~10.2 MB)
  char* wsp = (char*)d_ws;
  int* fidx = (int*)wsp;
  int* nidx = (int*)(wsp + (32 << 10));
  float* xyzA = (float*)(wsp + (32 << 10) + (2 << 20));
  float* xyzB = xyzA + B_SZ * 2048 * 3;
  float* featA = xyzB + B_SZ * 2048 * 3;
  float* featB = featA + B_SZ * 2048 * 128;
  float* oxyz = (float*)d_out;           // [4,256,3]
  float* ofeat = oxyz + B_SZ * 256 * 3;  // [4,256,512]

  // ---------------- Stage 1: N=16384 -> S=2048, r=0.2, ns=64, 3->64->64->128
  hipLaunchKernelGGL((fps_kernel<16384, 2048, 512, false>), dim3(B_SZ), dim3(512), 0, stream,
                     pc, fidx);
  hipLaunchKernelGGL(gather_xyz_kernel, dim3(32, B_SZ), dim3(64), 0, stream,
                     pc, fidx, xyzA, 16384, 2048);
  hipLaunchKernelGGL((ball_query_kernel<16384, 64>), dim3(512, B_SZ), dim3(256), 0, stream,
                     pc, xyzA, nidx, 2048, (float)(0.2 * 0.2));
  hipLaunchKernelGGL((group_mlp_kernel<64, 1, 0, 64, 64, 128, 8, 32, 128>),
                     dim3(2048, B_SZ), dim3(256), 0, stream,
                     pc, xyzA, (const float*)nullptr, nidx,
                     W[0][0], Bb[0][0], W[0][1], Bb[0][1], W[0][2], Bb[0][2],
                     featA, 16384, 2048, 0.2f);

  // ---------------- Stage 2: N=2048 -> S=1024, r=0.4, ns=32, 131->128->128->256
  hipLaunchKernelGGL((fps_kernel<2048, 1024, 512, true>), dim3(B_SZ), dim3(512), 0, stream,
                     xyzA, fidx);
  hipLaunchKernelGGL(gather_xyz_kernel, dim3(16, B_SZ), dim3(64), 0, stream,
                     xyzA, fidx, xyzB, 2048, 1024);
  hipLaunchKernelGGL((ball_query_kernel<2048, 32>), dim3(256, B_SZ), dim3(256), 0, stream,
                     xyzA, xyzB, nidx, 1024, (float)(0.4 * 0.4));
  hipLaunchKernelGGL((group_mlp_kernel<32, 1, 128, 128, 128, 256, 4, 64, 256>),
                     dim3(1024, B_SZ), dim3(256), 0, stream,
                     xyzA, xyzB, featA, nidx,
                     W[1][0], Bb[1][0], W[1][1], Bb[1][1], W[1][2], Bb[1][2],
                     featB, 2048, 1024, 0.4f);

  // ---------------- Stage 3: N=1024 -> S=512, r=0.6, ns=16, 259->256->256->512
  hipLaunchKernelGGL((fps_kernel<1024, 512, 256, true>), dim3(B_SZ), dim3(256), 0, stream,
                     xyzB, fidx);
  hipLaunchKernelGGL(gather_xyz_kernel, dim3(8, B_SZ), dim3(64), 0, stream,
                     xyzB, fidx, xyzA, 1024, 512);
  hipLaunchKernelGGL((ball_query_kernel<1024, 16>), dim3(128, B_SZ), dim3(256), 0, stream,
                     xyzB, xyzA, nidx, 512, (float)(0.6 * 0.6));
  hipLaunchKernelGGL((group_mlp_kernel<16, 1, 256, 256, 256, 512, 2, 128, 512>),
                     dim3(512, B_SZ), dim3(256), 0, stream,
                     xyzB, xyzA, featB, nidx,
                     W[2][0], Bb[2][0], W[2][1], Bb[2][1], W[2][2], Bb[2][2],
                     featA, 1024, 512, 0.6f);

  // ---------------- Stage 4: N=512 -> S=256, r=1.2, ns=8, 515->512->512->512
  hipLaunchKernelGGL((fps_kernel<512, 256, 256, true>), dim3(B_SZ), dim3(256), 0, stream,
                     xyzA, fidx);
  hipLaunchKernelGGL(gather_xyz_kernel, dim3(4, B_SZ), dim3(64), 0, stream,
                     xyzA, fidx, oxyz, 512, 256);
  hipLaunchKernelGGL((ball_query_kernel<512, 8>), dim3(64, B_SZ), dim3(256), 0, stream,
                     xyzA, oxyz, nidx, 256, (float)(1.2 * 1.2));
  hipLaunchKernelGGL((group_mlp_kernel<8, 2, 512, 512, 512, 512, 2, 128, 516>),
                     dim3(128, B_SZ), dim3(256), 0, stream,
                     xyzA, oxyz, featA, nidx,
                     W[3][0], Bb[3][0], W[3][1], Bb[3][1], W[3][2], Bb[3][2],
                     ofeat, 512, 256, 1.2f);
}

// Round 4
// 5275.056 us; speedup vs baseline: 1.1611x; 1.1611x over previous
//
#include <hip/hip_runtime.h>
#include <hip/hip_bf16.h>

// ---------------------------------------------------------------------------
// PointNet++ encoder (4 SA stages) for MI355X.
// Pipeline per stage: FPS -> gather new_xyz -> ball query -> fused group+MLP+maxpool.
// FPS / ball-query distance math matches numpy per-op IEEE semantics exactly
// (argmax selection must be exact; xyz output is raw copies).
// ---------------------------------------------------------------------------

#define B_SZ 4

typedef float v2f __attribute__((ext_vector_type(2)));

// Packed-FP32 helpers (VOP3P). Each half is a plain IEEE f32 op, so results
// are bitwise identical to scalar v_add_f32/v_mul_f32.
__device__ __forceinline__ v2f pk_add(v2f a, v2f b) {
  v2f d;
  asm("v_pk_add_f32 %0, %1, %2" : "=v"(d) : "v"(a), "v"(b));
  return d;
}
__device__ __forceinline__ v2f pk_mul(v2f a, v2f b) {
  v2f d;
  asm("v_pk_mul_f32 %0, %1, %2" : "=v"(d) : "v"(a), "v"(b));
  return d;
}

// DPP neighbor-fetch on a packed u64 (two 32-bit DPP moves). With
// bound_ctrl=false + full masks, lanes with no valid source keep `old`
// (their own value), so max() with the result is a no-op there.
template <int CTRL>
__device__ __forceinline__ unsigned long long dpp_u64(unsigned long long v) {
  int lo = (int)(unsigned)v;
  int hi = (int)(unsigned)(v >> 32);
  int nlo = __builtin_amdgcn_update_dpp(lo, lo, CTRL, 0xF, 0xF, false);
  int nhi = __builtin_amdgcn_update_dpp(hi, hi, CTRL, 0xF, 0xF, false);
  return ((unsigned long long)(unsigned)nhi << 32) | (unsigned)nlo;
}

// Full-wave (64-lane) max reduce on VALU pipe: row_shr 1/2/4/8 builds per-16
// row max in lane 15 of each row; row_bcast15/31 fold rows. Result in lane 63.
__device__ __forceinline__ unsigned long long wave_max_u64(unsigned long long P) {
  unsigned long long o;
  o = dpp_u64<0x111>(P); P = o > P ? o : P;  // row_shr:1
  o = dpp_u64<0x112>(P); P = o > P ? o : P;  // row_shr:2
  o = dpp_u64<0x114>(P); P = o > P ? o : P;  // row_shr:4
  o = dpp_u64<0x118>(P); P = o > P ? o : P;  // row_shr:8
  o = dpp_u64<0x142>(P); P = o > P ? o : P;  // row_bcast15
  o = dpp_u64<0x143>(P); P = o > P ? o : P;  // row_bcast31
  return P;
}

// ------------------------------- FPS ---------------------------------------
// One block per batch; ONE barrier per iteration.
// Per-thread: packed-fp32 distance update (2 points per instruction bundle),
// argmax tracked as (float, k) in up to 4 contiguous-k chains (strict > keeps
// the first occurrence = smallest index). Packed u64 (dist_bits<<32 | N-idx)
// is built once per thread, wave-reduced via DPP (VALU pipe, ~120cy vs ~800cy
// for ds_swizzle shuffles), then NW wave results are combined by a redundant
// LDS scan (no second barrier; double-buffered slots).
template <int N, int NPOINT, int T, bool XYZ_IN_LDS>
__global__ __launch_bounds__(T) void fps_kernel(const float* __restrict__ xyz,
                                                int* __restrict__ fidx) {
#pragma clang fp contract(off)
  constexpr int PT = N / T;
  static_assert(PT % 2 == 0, "PT even");
  constexpr int NP2 = PT / 2;
  constexpr int NW = T / 64;
  constexpr int NCH = (NP2 >= 4) ? 4 : NP2;  // independent tracking chains
  constexpr int CW = NP2 / NCH;              // pairs per chain (contiguous k)
  constexpr int LN = XYZ_IN_LDS ? N : 1;
  const int b = blockIdx.x;
  const int t = threadIdx.x;
  const int lane = t & 63;
  const int wv = t >> 6;
  const float* base = xyz + (size_t)b * N * 3;

  v2f px[NP2], py[NP2], pz[NP2], dv[NP2];
  __shared__ __align__(16) unsigned long long s_pack[2][NW];
  __shared__ float s_x[LN], s_y[LN], s_z[LN];

#pragma unroll
  for (int j = 0; j < NP2; ++j) {
    int i0 = t + (2 * j) * T;
    int i1 = t + (2 * j + 1) * T;
    px[j][0] = base[i0 * 3 + 0];
    py[j][0] = base[i0 * 3 + 1];
    pz[j][0] = base[i0 * 3 + 2];
    px[j][1] = base[i1 * 3 + 0];
    py[j][1] = base[i1 * 3 + 1];
    pz[j][1] = base[i1 * 3 + 2];
    dv[j][0] = 1e10f;
    dv[j][1] = 1e10f;
    if constexpr (XYZ_IN_LDS) {
      s_x[i0] = px[j][0];
      s_y[i0] = py[j][0];
      s_z[i0] = pz[j][0];
      s_x[i1] = px[j][1];
      s_y[i1] = py[j][1];
      s_z[i1] = pz[j][1];
    }
  }
  __syncthreads();

  int far = 0;
  int p = 0;
  for (int it = 0; it < NPOINT; ++it) {
    if (t == 0) fidx[b * NPOINT + it] = far;
    float cx, cy, cz;
    if constexpr (XYZ_IN_LDS) {
      cx = s_x[far];
      cy = s_y[far];
      cz = s_z[far];
    } else {
      cx = base[far * 3 + 0];
      cy = base[far * 3 + 1];
      cz = base[far * 3 + 2];
    }
    // (p - c) computed as p + (-c): bitwise identical to IEEE subtraction.
    const float nx = -cx, ny = -cy, nz = -cz;
    const v2f c2x = {nx, nx}, c2y = {ny, ny}, c2z = {nz, nz};

    float best[NCH];
    int bk[NCH];
#pragma unroll
    for (int q = 0; q < NCH; ++q) {
      best[q] = -1.0f;
      bk[q] = 0;
    }

#pragma unroll
    for (int j = 0; j < NP2; ++j) {
      v2f dx = pk_add(px[j], c2x);
      v2f dy = pk_add(py[j], c2y);
      v2f dz = pk_add(pz[j], c2z);
      v2f xx = pk_mul(dx, dx);
      v2f yy = pk_mul(dy, dy);
      v2f zz = pk_mul(dz, dz);
      v2f s = pk_add(xx, yy);
      v2f d = pk_add(s, zz);
      v2f nd;
      nd[0] = fminf(dv[j][0], d[0]);
      nd[1] = fminf(dv[j][1], d[1]);
      dv[j] = nd;
      const int q = j / CW;  // compile-time (loop unrolled)
      if (nd[0] > best[q]) {
        best[q] = nd[0];
        bk[q] = 2 * j;
      }
      if (nd[1] > best[q]) {
        best[q] = nd[1];
        bk[q] = 2 * j + 1;
      }
    }
    // merge chains in ascending-k order; strict > keeps smallest index on tie
    float bb = best[0];
    int kk = bk[0];
#pragma unroll
    for (int q = 1; q < NCH; ++q) {
      if (best[q] > bb) {
        bb = best[q];
        kk = bk[q];
      }
    }
    int idx = t + kk * T;
    unsigned long long P =
        ((unsigned long long)__float_as_uint(bb) << 32) |
        (unsigned int)(N - idx);
    // wave max-reduce on packed u64 via DPP (result valid in lane 63)
    P = wave_max_u64(P);
    if (lane == 63) s_pack[p][wv] = P;
    __syncthreads();
    unsigned long long bbp = s_pack[p][0];
#pragma unroll
    for (int w = 1; w < NW; ++w) {
      unsigned long long v = s_pack[p][w];
      bbp = v > bbp ? v : bbp;
    }
    far = N - (int)(unsigned int)(bbp & 0xffffffffull);
    p ^= 1;
  }
}

// --------------------------- gather new_xyz --------------------------------
__global__ void gather_xyz_kernel(const float* __restrict__ xyz,
                                  const int* __restrict__ fidx,
                                  float* __restrict__ out, int N, int S) {
  int s = blockIdx.x * blockDim.x + threadIdx.x;
  int b = blockIdx.y;
  if (s < S) {
    int i = fidx[b * S + s];
    out[((size_t)(b * S + s)) * 3 + 0] = xyz[((size_t)(b * N + i)) * 3 + 0];
    out[((size_t)(b * S + s)) * 3 + 1] = xyz[((size_t)(b * N + i)) * 3 + 1];
    out[((size_t)(b * S + s)) * 3 + 2] = xyz[((size_t)(b * N + i)) * 3 + 2];
  }
}

// ----------------------------- ball query ----------------------------------
// One wave per query point. Scan N points in 64-chunks; ballot-ordered append
// of in-ball indices (ascending index = reference's sort semantics); pad with
// first neighbor. d2 formula replicates (|c|^2 + |x|^2) - 2*dot, contract off.
template <int N, int NS>
__global__ __launch_bounds__(256) void ball_query_kernel(
    const float* __restrict__ xyz, const float* __restrict__ new_xyz,
    int* __restrict__ nidx, int S, float r2) {
#pragma clang fp contract(off)
  const int wv = threadIdx.x >> 6;
  const int lane = threadIdx.x & 63;
  const int b = blockIdx.y;
  const int s = blockIdx.x * 4 + wv;
  __shared__ int s_idx[4][NS];
  const float* base = xyz + (size_t)b * N * 3;

  float cx = new_xyz[((size_t)(b * S + s)) * 3 + 0];
  float cy = new_xyz[((size_t)(b * S + s)) * 3 + 1];
  float cz = new_xyz[((size_t)(b * S + s)) * 3 + 2];
  float sc = (cx * cx + cy * cy) + cz * cz;

  int found = 0;
  for (int i0 = 0; i0 < N && found < NS; i0 += 64) {  // N % 64 == 0 always
    int i = i0 + lane;
    float x = base[i * 3 + 0];
    float y = base[i * 3 + 1];
    float z = base[i * 3 + 2];
    float sx = (x * x + y * y) + z * z;
    float dt = (cx * x + cy * y) + cz * z;
    float d2 = (sc + sx) - 2.0f * dt;
    bool inb = d2 < r2;
    unsigned long long m = __ballot(inb);
    if (inb) {
      int pos = found + __popcll(m & ((1ull << lane) - 1));
      if (pos < NS) s_idx[wv][pos] = i;
    }
    found += __popcll(m);
  }
  __syncthreads();
  int fcnt = found < NS ? found : NS;
  int first = s_idx[wv][0];
  int* outp = nidx + ((size_t)(b * S + s)) * NS;
  for (int j = lane; j < NS; j += 64) outp[j] = (j < fcnt) ? s_idx[wv][j] : first;
}

// --------------------------- fused group MLP -------------------------------
// act[R][CMAXP] in LDS holds activations in-place across the 3 layers.
// Thread grid RG x CG; each thread owns RPT rows x CPT cols; W streamed from
// L1/L2 (each W element feeds RPT FMAs).
template <int R, int RG, int CG, int CMAXP, int CIN, int COUT>
__device__ __forceinline__ void mlp_layer(float* act, const float* __restrict__ w,
                                          const float* __restrict__ bias, int tid) {
  constexpr int RPT = R / RG;
  constexpr int CPT = COUT / CG;
  static_assert(RG * CG == 256, "thread grid");
  const int rg = tid / CG;
  const int cg = tid % CG;

  float acc[RPT][CPT];
#pragma unroll
  for (int rr = 0; rr < RPT; ++rr)
#pragma unroll
    for (int cc = 0; cc < CPT; ++cc) acc[rr][cc] = 0.f;

  constexpr int K4 = (CIN / 4) * 4;
  for (int k = 0; k < K4; k += 4) {
    float4 a[RPT];
#pragma unroll
    for (int rr = 0; rr < RPT; ++rr)
      a[rr] = *(const float4*)(&act[(rg * RPT + rr) * CMAXP + k]);
    float wvv[4][CPT];
#pragma unroll
    for (int kk = 0; kk < 4; ++kk)
#pragma unroll
      for (int cc = 0; cc < CPT; ++cc)
        wvv[kk][cc] = w[(size_t)(k + kk) * COUT + cg + cc * CG];
#pragma unroll
    for (int rr = 0; rr < RPT; ++rr) {
      float4 av = a[rr];
#pragma unroll
      for (int cc = 0; cc < CPT; ++cc) {
        acc[rr][cc] += av.x * wvv[0][cc];
        acc[rr][cc] += av.y * wvv[1][cc];
        acc[rr][cc] += av.z * wvv[2][cc];
        acc[rr][cc] += av.w * wvv[3][cc];
      }
    }
  }
#pragma unroll 1
  for (int k = K4; k < CIN; ++k) {
    float wvv[CPT];
#pragma unroll
    for (int cc = 0; cc < CPT; ++cc) wvv[cc] = w[(size_t)k * COUT + cg + cc * CG];
#pragma unroll
    for (int rr = 0; rr < RPT; ++rr) {
      float av = act[(rg * RPT + rr) * CMAXP + k];
#pragma unroll
      for (int cc = 0; cc < CPT; ++cc) acc[rr][cc] += av * wvv[cc];
    }
  }
  __syncthreads();  // all reads of act done before in-place overwrite
#pragma unroll
  for (int rr = 0; rr < RPT; ++rr)
#pragma unroll
    for (int cc = 0; cc < CPT; ++cc) {
      int co = cg + cc * CG;
      float v = acc[rr][cc] + bias[co];
      act[(rg * RPT + rr) * CMAXP + co] = fmaxf(v, 0.f);
    }
  __syncthreads();
}

template <int NS, int G, int CPREV, int CO0, int CO1, int CO2, int RG, int CG, int CMAXP>
__global__ __launch_bounds__(256) void group_mlp_kernel(
    const float* __restrict__ xyz, const float* __restrict__ new_xyz,
    const float* __restrict__ feats, const int* __restrict__ nidx,
    const float* __restrict__ w0, const float* __restrict__ b0,
    const float* __restrict__ w1, const float* __restrict__ b1,
    const float* __restrict__ w2, const float* __restrict__ b2,
    float* __restrict__ out, int N, int S, float radius) {
  constexpr int R = NS * G;
  constexpr int CIN = 3 + CPREV;
  __shared__ __align__(16) float act[R * CMAXP];
  const int tid = threadIdx.x;
  const int b = blockIdx.y;
  const int s0 = blockIdx.x * G;

  // stage inputs: rel xyz (exact sub + div by radius) and gathered feats
  for (int i = tid; i < R * CIN; i += 256) {
    int row = i / CIN;
    int ch = i - row * CIN;
    int g = row / NS;
    int j = row - g * NS;
    int sidx = s0 + g;
    int n = nidx[((size_t)(b * S + sidx)) * NS + j];
    float v;
    if constexpr (CPREV == 0) {
      v = (xyz[((size_t)(b * N + n)) * 3 + ch] -
           new_xyz[((size_t)(b * S + sidx)) * 3 + ch]) /
          radius;
    } else {
      if (ch < 3) {
        v = (xyz[((size_t)(b * N + n)) * 3 + ch] -
             new_xyz[((size_t)(b * S + sidx)) * 3 + ch]) /
            radius;
      } else {
        v = feats[((size_t)(b * N + n)) * CPREV + (ch - 3)];
      }
    }
    act[row * CMAXP + ch] = v;
  }
  __syncthreads();

  mlp_layer<R, RG, CG, CMAXP, CIN, CO0>(act, w0, b0, tid);
  mlp_layer<R, RG, CG, CMAXP, CO0, CO1>(act, w1, b1, tid);
  mlp_layer<R, RG, CG, CMAXP, CO1, CO2>(act, w2, b2, tid);

  // maxpool over NS neighbors per group
  for (int i = tid; i < G * CO2; i += 256) {
    int g = i / CO2;
    int co = i - g * CO2;
    float m = act[(g * NS) * CMAXP + co];
    for (int j = 1; j < NS; ++j) m = fmaxf(m, act[(g * NS + j) * CMAXP + co]);
    out[((size_t)(b * S + s0 + g)) * CO2 + co] = m;
  }
}

// ---------------------------------------------------------------------------
extern "C" void kernel_launch(void* const* d_in, const int* in_sizes, int n_in,
                              void* d_out, int out_size, void* d_ws, size_t ws_size,
                              hipStream_t stream) {
  (void)in_sizes; (void)n_in; (void)out_size; (void)ws_size;
  const float* pc = (const float*)d_in[0];
  const float* W[4][3];
  const float* Bb[4][3];
  for (int s = 0; s < 4; ++s)
    for (int l = 0; l < 3; ++l) {
      W[s][l] = (const float*)d_in[1 + s * 6 + l * 2];
      Bb[s][l] = (const float*)d_in[2 + s * 6 + l * 2];
    }

  // workspace layout (bytes): fidx 32KB | nidx 2MB | xyzA 96KB | xyzB 96KB |
  // featA 4MB | featB 4MB   (total ~10.2 MB)
  char* wsp = (char*)d_ws;
  int* fidx = (int*)wsp;
  int* nidx = (int*)(wsp + (32 << 10));
  float* xyzA = (float*)(wsp + (32 << 10) + (2 << 20));
  float* xyzB = xyzA + B_SZ * 2048 * 3;
  float* featA = xyzB + B_SZ * 2048 * 3;
  float* featB = featA + B_SZ * 2048 * 128;
  float* oxyz = (float*)d_out;           // [4,256,3]
  float* ofeat = oxyz + B_SZ * 256 * 3;  // [4,256,512]

  // ---------------- Stage 1: N=16384 -> S=2048, r=0.2, ns=64, 3->64->64->128
  hipLaunchKernelGGL((fps_kernel<16384, 2048, 512, false>), dim3(B_SZ), dim3(512), 0, stream,
                     pc, fidx);
  hipLaunchKernelGGL(gather_xyz_kernel, dim3(32, B_SZ), dim3(64), 0, stream,
                     pc, fidx, xyzA, 16384, 2048);
  hipLaunchKernelGGL((ball_query_kernel<16384, 64>), dim3(512, B_SZ), dim3(256), 0, stream,
                     pc, xyzA, nidx, 2048, (float)(0.2 * 0.2));
  hipLaunchKernelGGL((group_mlp_kernel<64, 1, 0, 64, 64, 128, 8, 32, 128>),
                     dim3(2048, B_SZ), dim3(256), 0, stream,
                     pc, xyzA, (const float*)nullptr, nidx,
                     W[0][0], Bb[0][0], W[0][1], Bb[0][1], W[0][2], Bb[0][2],
                     featA, 16384, 2048, 0.2f);

  // ---------------- Stage 2: N=2048 -> S=1024, r=0.4, ns=32, 131->128->128->256
  hipLaunchKernelGGL((fps_kernel<2048, 1024, 512, true>), dim3(B_SZ), dim3(512), 0, stream,
                     xyzA, fidx);
  hipLaunchKernelGGL(gather_xyz_kernel, dim3(16, B_SZ), dim3(64), 0, stream,
                     xyzA, fidx, xyzB, 2048, 1024);
  hipLaunchKernelGGL((ball_query_kernel<2048, 32>), dim3(256, B_SZ), dim3(256), 0, stream,
                     xyzA, xyzB, nidx, 1024, (float)(0.4 * 0.4));
  hipLaunchKernelGGL((group_mlp_kernel<32, 1, 128, 128, 128, 256, 4, 64, 256>),
                     dim3(1024, B_SZ), dim3(256), 0, stream,
                     xyzA, xyzB, featA, nidx,
                     W[1][0], Bb[1][0], W[1][1], Bb[1][1], W[1][2], Bb[1][2],
                     featB, 2048, 1024, 0.4f);

  // ---------------- Stage 3: N=1024 -> S=512, r=0.6, ns=16, 259->256->256->512
  hipLaunchKernelGGL((fps_kernel<1024, 512, 256, true>), dim3(B_SZ), dim3(256), 0, stream,
                     xyzB, fidx);
  hipLaunchKernelGGL(gather_xyz_kernel, dim3(8, B_SZ), dim3(64), 0, stream,
                     xyzB, fidx, xyzA, 1024, 512);
  hipLaunchKernelGGL((ball_query_kernel<1024, 16>), dim3(128, B_SZ), dim3(256), 0, stream,
                     xyzB, xyzA, nidx, 512, (float)(0.6 * 0.6));
  hipLaunchKernelGGL((group_mlp_kernel<16, 1, 256, 256, 256, 512, 2, 128, 512>),
                     dim3(512, B_SZ), dim3(256), 0, stream,
                     xyzB, xyzA, featB, nidx,
                     W[2][0], Bb[2][0], W[2][1], Bb[2][1], W[2][2], Bb[2][2],
                     featA, 1024, 512, 0.6f);

  // ---------------- Stage 4: N=512 -> S=256, r=1.2, ns=8, 515->512->512->512
  hipLaunchKernelGGL((fps_kernel<512, 256, 256, true>), dim3(B_SZ), dim3(256), 0, stream,
                     xyzA, fidx);
  hipLaunchKernelGGL(gather_xyz_kernel, dim3(4, B_SZ), dim3(64), 0, stream,
                     xyzA, fidx, oxyz, 512, 256);
  hipLaunchKernelGGL((ball_query_kernel<512, 8>), dim3(64, B_SZ), dim3(256), 0, stream,
                     xyzA, oxyz, nidx, 256, (float)(1.2 * 1.2));
  hipLaunchKernelGGL((group_mlp_kernel<8, 2, 512, 512, 512, 512, 2, 128, 516>),
                     dim3(128, B_SZ), dim3(256), 0, stream,
                     xyzA, oxyz, featA, nidx,
                     W[3][0], Bb[3][0], W[3][1], Bb[3][1], W[3][2], Bb[3][2],
                     ofeat, 512, 256, 1.2f);
}